// Round 1
// baseline (4798.482 us; speedup 1.0000x reference)
//
#include <hip/hip_runtime.h>
#include <hip/hip_bf16.h>
#include <cstdint>
#include <cstddef>

#define B_ 128
#define T_ 1024
#define I_ 256
#define H_ 512
#define M_ (B_*T_)   // 131072

typedef __attribute__((ext_vector_type(4))) float floatx4;
typedef __attribute__((ext_vector_type(8))) short short8;

__device__ __forceinline__ unsigned short f2bf(float f) {
    union { float f; unsigned u; } v; v.f = f;
    unsigned r = v.u + 0x7FFFu + ((v.u >> 16) & 1u);
    return (unsigned short)(r >> 16);
}

// ---------------- cast fp32 -> bf16 (vectorized by 4) ----------------
__global__ __launch_bounds__(256) void cast_kernel(const float* __restrict__ in,
                                                   unsigned short* __restrict__ out,
                                                   int n4) {
    int i = blockIdx.x * 256 + threadIdx.x;
    if (i >= n4) return;
    float4 f = ((const float4*)in)[i];
    ushort4 o;
    o.x = f2bf(f.x); o.y = f2bf(f.y); o.z = f2bf(f.z); o.w = f2bf(f.w);
    ((ushort4*)out)[i] = o;
}

// ---------------- Wh transpose + cast: WhT[k][j] = Wh[j][k] ----------------
__global__ __launch_bounds__(256) void transpose_cast_wh(const float* __restrict__ Wh,
                                                         unsigned short* __restrict__ WhT) {
    int e = blockIdx.x * 256 + threadIdx.x;   // 262144 elements
    int j = e >> 9;          // row in Wh
    int k = e & 511;         // col in Wh
    WhT[(size_t)k * H_ + j] = f2bf(Wh[e]);
}

// ---------------- igates GEMM: out[M,H] = Xb[M,I] @ Wib[H,I]^T + bi ----------------
#define BM 128
#define BN 128
#define BK 32

__global__ __launch_bounds__(256) void gemm_igates(
    const unsigned short* __restrict__ Xb,   // [M_, I_] bf16
    const unsigned short* __restrict__ Wib,  // [H_, I_] bf16 (N x K)
    const float* __restrict__ bi,            // [H_]
    float* __restrict__ out)                 // [M_, H_] fp32
{
    __shared__ unsigned short As[BM * BK];
    __shared__ unsigned short Bs[BN * BK];
    const int tid  = threadIdx.x;
    const int wave = tid >> 6;
    const int lane = tid & 63;
    const int quad = lane >> 4;
    const int l16  = lane & 15;
    const int bm = blockIdx.x;
    const int bn = blockIdx.y;
    const int wm = (wave >> 1) * 64;
    const int wn = (wave & 1) * 64;

    floatx4 acc[4][4] = {};

    for (int k0 = 0; k0 < I_; k0 += BK) {
        #pragma unroll
        for (int it = 0; it < 2; ++it) {
            int c   = it * 256 + tid;        // 16-byte chunk index (512 per buffer)
            int row = c >> 2;                // 4 chunks per 32-elem row
            int col = (c & 3) * 8;
            const unsigned short* ga = Xb  + (size_t)(bm * BM + row) * I_ + k0 + col;
            const unsigned short* gb = Wib + (size_t)(bn * BN + row) * I_ + k0 + col;
            int base = (it * 256 + wave * 64) * 8;   // wave-uniform LDS chunk base (shorts)
            __builtin_amdgcn_global_load_lds(
                (const __attribute__((address_space(1))) void*)ga,
                (__attribute__((address_space(3))) void*)(As + base), 16, 0, 0);
            __builtin_amdgcn_global_load_lds(
                (const __attribute__((address_space(1))) void*)gb,
                (__attribute__((address_space(3))) void*)(Bs + base), 16, 0, 0);
        }
        __syncthreads();

        short8 af[4], bfr[4];
        #pragma unroll
        for (int i = 0; i < 4; ++i) {
            af[i]  = *(const short8*)(As + (wm + i * 16 + l16) * BK + quad * 8);
            bfr[i] = *(const short8*)(Bs + (wn + i * 16 + l16) * BK + quad * 8);
        }
        #pragma unroll
        for (int mi = 0; mi < 4; ++mi)
            #pragma unroll
            for (int ni = 0; ni < 4; ++ni)
                acc[mi][ni] = __builtin_amdgcn_mfma_f32_16x16x32_bf16(
                    af[mi], bfr[ni], acc[mi][ni], 0, 0, 0);
        __syncthreads();
    }

    #pragma unroll
    for (int mi = 0; mi < 4; ++mi) {
        #pragma unroll
        for (int ni = 0; ni < 4; ++ni) {
            int col = bn * BN + wn + ni * 16 + l16;
            float bv = bi[col];
            #pragma unroll
            for (int r = 0; r < 4; ++r) {
                int row = bm * BM + wm + mi * 16 + quad * 4 + r;
                out[(size_t)row * H_ + col] = acc[mi][ni][r] + bv;
            }
        }
    }
}

// ---------------- recurrent scan: one block per batch, T-loop inside ----------------
// WhT[k][j] = Wh[j][k] (bf16). SAXPY form: h_new[j] = sum_k h[k] * WhT[k][j].
// wave = k-group (64 k's), lane = 8 consecutive j's (one uint4 = 8 bf16 per load,
// fully coalesced). Cross-wave reduction via LDS partials.
__global__ __launch_bounds__(512) void scan_kernel(
    const unsigned short* __restrict__ WhT,  // [H_, H_] bf16
    const float* __restrict__ h0,            // [B_, H_]
    const float* __restrict__ bh,            // [H_]
    float* __restrict__ out,                 // [B_, T_, H_] (holds igates fp32 on entry)
    float* __restrict__ hlast)               // [B_, H_]
{
    __shared__ __align__(16) float h[H_];
    __shared__ __align__(16) float partial[8][H_];   // 16 KB
    const int b   = blockIdx.x;
    const int tid = threadIdx.x;
    const int kg  = tid >> 6;    // wave id: k-group
    const int jc  = tid & 63;    // lane: j-chunk (8 outputs)

    h[tid] = h0[(size_t)b * H_ + tid];
    const float bj = bh[tid];
    float* obase = out + (size_t)b * T_ * H_;
    const uint4* wp = (const uint4*)WhT + (size_t)kg * 64 * 64 + jc;  // row kg*64, cols jc*8..
    __syncthreads();

    for (int t = 0; t < T_; ++t) {
        float4 p0 = {0.f, 0.f, 0.f, 0.f};
        float4 p1 = {0.f, 0.f, 0.f, 0.f};
        #pragma unroll 8
        for (int kk = 0; kk < 64; ++kk) {
            uint4 wv = wp[(size_t)kk * 64];       // WhT[kg*64+kk][jc*8 .. jc*8+7]
            float hk = h[kg * 64 + kk];           // wave-uniform broadcast
            union { unsigned u; float f; } a0, a1, a2, a3, a4, a5, a6, a7;
            a0.u = wv.x << 16; a1.u = wv.x & 0xFFFF0000u;
            a2.u = wv.y << 16; a3.u = wv.y & 0xFFFF0000u;
            a4.u = wv.z << 16; a5.u = wv.z & 0xFFFF0000u;
            a6.u = wv.w << 16; a7.u = wv.w & 0xFFFF0000u;
            p0.x += hk * a0.f; p0.y += hk * a1.f;
            p0.z += hk * a2.f; p0.w += hk * a3.f;
            p1.x += hk * a4.f; p1.y += hk * a5.f;
            p1.z += hk * a6.f; p1.w += hk * a7.f;
        }
        ((float4*)&partial[kg][jc * 8])[0] = p0;
        ((float4*)&partial[kg][jc * 8])[1] = p1;
        __syncthreads();

        int j = tid;
        float s = partial[0][j] + partial[1][j] + partial[2][j] + partial[3][j]
                + partial[4][j] + partial[5][j] + partial[6][j] + partial[7][j];
        float acc = obase[(size_t)t * H_ + j] + bj + s;
        float hv  = 1.0f / (1.0f + __expf(-acc));
        obase[(size_t)t * H_ + j] = hv;
        h[j] = hv;                    // safe: all reads of old h finished before barrier above
        __syncthreads();
    }
    hlast[(size_t)b * H_ + tid] = h[tid];
}

extern "C" void kernel_launch(void* const* d_in, const int* in_sizes, int n_in,
                              void* d_out, int out_size, void* d_ws, size_t ws_size,
                              hipStream_t stream) {
    const float* x  = (const float*)d_in[0];   // [B,T,I]
    const float* h0 = (const float*)d_in[1];   // [B,H]
    const float* Wi = (const float*)d_in[2];   // [H,I]
    const float* bi = (const float*)d_in[3];   // [H]
    const float* Wh = (const float*)d_in[4];   // [H,H]
    const float* bh = (const float*)d_in[5];   // [H]
    float* out = (float*)d_out;

    unsigned short* Xb  = (unsigned short*)d_ws;            // M_*I_ bf16 = 64 MB
    unsigned short* Wib = Xb  + (size_t)M_ * I_;            // H_*I_ bf16
    unsigned short* WhT = Wib + (size_t)H_ * I_;            // H_*H_ bf16 (transposed)

    // casts
    cast_kernel<<<(M_ * I_ / 4 + 255) / 256, 256, 0, stream>>>(x, Xb, M_ * I_ / 4);
    cast_kernel<<<(H_ * I_ / 4 + 255) / 256, 256, 0, stream>>>(Wi, Wib, H_ * I_ / 4);
    transpose_cast_wh<<<(H_ * H_) / 256, 256, 0, stream>>>(Wh, WhT);

    // igates = x @ Wi^T + bi  -> written into d_out in-place (scan overwrites with h)
    dim3 ggrid(M_ / BM, H_ / BN);
    gemm_igates<<<ggrid, 256, 0, stream>>>(Xb, Wib, bi, out);

    // sequential scan, one block per batch
    scan_kernel<<<B_, H_, 0, stream>>>(WhT, h0, bh, out, out + (size_t)M_ * H_);
}